// Round 12
// baseline (471.539 us; speedup 1.0000x reference)
//
#include <hip/hip_runtime.h>
#include <cstdint>
#include <cstddef>

#define HD   1024
#define SEQL 200
#define MEMN 50
#define RTOT 51200   // 256 * 200

typedef float  f4    __attribute__((ext_vector_type(4)));
typedef float  f32x4 __attribute__((ext_vector_type(4)));
typedef short  s16x8 __attribute__((ext_vector_type(8)));
typedef unsigned short u16;
typedef unsigned short u16x4 __attribute__((ext_vector_type(4)));
typedef unsigned short u16x8 __attribute__((ext_vector_type(8)));

__device__ __forceinline__ u16 f2bf(float f) {
    unsigned u = __builtin_bit_cast(unsigned, f);
    u += 0x7FFFu + ((u >> 16) & 1u);          // RNE
    return (u16)(u >> 16);
}
__device__ __forceinline__ float bf2f(u16 h) {
    unsigned u = ((unsigned)h) << 16;
    return __builtin_bit_cast(float, u);
}

#define GLOAD_LDS16(g, l) __builtin_amdgcn_global_load_lds( \
    (const __attribute__((address_space(1))) unsigned int*)(g), \
    (__attribute__((address_space(3))) unsigned int*)(l), 16, 0, 0)

#define WAITV4 asm volatile("s_waitcnt vmcnt(4)" ::: "memory")
#define WAITV3 asm volatile("s_waitcnt vmcnt(3)" ::: "memory")
#define WAITV0 asm volatile("s_waitcnt vmcnt(0)" ::: "memory")
#define SCHB   __builtin_amdgcn_sched_barrier(0)

// ---------------------------------------------------------------------------
// K0a: gate_w f32 -> bf16, layout [o][2048] k-contig. Wf = cols 0..1023,
//      Wm = cols 1024..2047.
// ---------------------------------------------------------------------------
__global__ __launch_bounds__(256) void k_cvt_w(const float* __restrict__ gw,
                                               u16* __restrict__ gwB)
{
    const size_t i = ((size_t)blockIdx.x * 256 + threadIdx.x) * 8;
    f4 v0 = *(const f4*)&gw[i];
    f4 v1 = *(const f4*)&gw[i + 4];
    u16x4 b0 = { f2bf(v0.x), f2bf(v0.y), f2bf(v0.z), f2bf(v0.w) };
    u16x4 b1 = { f2bf(v1.x), f2bf(v1.y), f2bf(v1.z), f2bf(v1.w) };
    *(u16x4*)&gwB[i]     = b0;
    *(u16x4*)&gwB[i + 4] = b1;
}

// ---------------------------------------------------------------------------
// K0b: spatial memory -> {memHi, memLo} [64][1024] bf16 (rows 50..63 zero)
//      and memT [1024][64] bf16 (hi, transposed, zero-padded).
// ---------------------------------------------------------------------------
__global__ __launch_bounds__(256) void k_prep_mem(const float* __restrict__ sm,
                                                  u16* __restrict__ memHi,
                                                  u16* __restrict__ memLo,
                                                  u16* __restrict__ memT)
{
    const int idx = blockIdx.x * 256 + threadIdx.x;   // 16384 total
    const int m  = idx >> 8;
    const int h0 = (idx & 255) * 4;
    f4 v = {0.f, 0.f, 0.f, 0.f};
    if (m < MEMN) v = *(const f4*)&sm[(size_t)m * HD + h0];
    u16x4 hi = { f2bf(v.x), f2bf(v.y), f2bf(v.z), f2bf(v.w) };
    f4 hv = { bf2f(hi.x), bf2f(hi.y), bf2f(hi.z), bf2f(hi.w) };
    f4 lv = v - hv;
    u16x4 lo = { f2bf(lv.x), f2bf(lv.y), f2bf(lv.z), f2bf(lv.w) };
    *(u16x4*)&memHi[(size_t)m * HD + h0] = hi;
    *(u16x4*)&memLo[(size_t)m * HD + h0] = lo;
    memT[(size_t)(h0 + 0) * 64 + m] = hi.x;
    memT[(size_t)(h0 + 1) * 64 + m] = hi.y;
    memT[(size_t)(h0 + 2) * 64 + m] = hi.z;
    memT[(size_t)(h0 + 3) * 64 + m] = hi.w;
}

// ---------------------------------------------------------------------------
// K0d: MWmT[o][m] = (M @ Wm)(m,o) as bf16, [1024][64].  MFMA, 16 blocks.
// ---------------------------------------------------------------------------
__global__ __launch_bounds__(256) void k_mwm(const u16* __restrict__ memHi,
                                             const u16* __restrict__ gwB,
                                             u16* __restrict__ MWmT)
{
    const int tid = threadIdx.x, lane = tid & 63, w = tid >> 6;
    const int fr = lane & 15, fk = (lane >> 4) * 8, jr = (lane >> 4) * 4;
    const int ob = blockIdx.x * 64 + w * 16;       // o-base of this wave
    f32x4 acc[4] = {};
    for (int ks = 0; ks < 32; ++ks) {
        s16x8 b = *(const s16x8*)&gwB[(size_t)(ob + fr) * 2048 + 1024 + ks * 32 + fk];
        #pragma unroll
        for (int mt = 0; mt < 4; ++mt) {
            s16x8 a = *(const s16x8*)&memHi[(size_t)(mt * 16 + fr) * HD + ks * 32 + fk];
            acc[mt] = __builtin_amdgcn_mfma_f32_16x16x32_bf16(a, b, acc[mt], 0, 0, 0);
        }
    }
    #pragma unroll
    for (int mt = 0; mt < 4; ++mt)
        #pragma unroll
        for (int j = 0; j < 4; ++j)
            MWmT[(size_t)(ob + fr) * 64 + mt * 16 + jr + j] = f2bf(acc[mt][j]);
}

// ---------------------------------------------------------------------------
// K1a: k_feats — pure streaming. feats = x + pos (f32);
//      featsB = bf16(feats); featsLo = bf16(feats - featsB).
//      1600 blocks x 256 thr x 8 elem x 16 sweeps = exactly RTOT*HD.
// ---------------------------------------------------------------------------
__global__ __launch_bounds__(256) void k_feats(const float* __restrict__ x,
                                               const float* __restrict__ pos,
                                               u16* __restrict__ featsB,
                                               u16* __restrict__ featsLo)
{
    const size_t stride = (size_t)gridDim.x * 256 * 8;
    for (size_t e = ((size_t)blockIdx.x * 256 + threadIdx.x) * 8;
         e < (size_t)RTOT * HD; e += stride) {
        const int row  = (int)(e >> 10);
        const int col  = (int)(e & 1023);
        const int prow = row % SEQL;
        f4 x0 = *(const f4*)&x[e];
        f4 x1 = *(const f4*)&x[e + 4];
        f4 p0 = *(const f4*)&pos[(size_t)prow * HD + col];
        f4 p1 = *(const f4*)&pos[(size_t)prow * HD + col + 4];
        f4 fa = x0 + p0, fb = x1 + p1;
        u16x8 hi = { f2bf(fa.x), f2bf(fa.y), f2bf(fa.z), f2bf(fa.w),
                     f2bf(fb.x), f2bf(fb.y), f2bf(fb.z), f2bf(fb.w) };
        f4 hv0 = { bf2f(hi[0]), bf2f(hi[1]), bf2f(hi[2]), bf2f(hi[3]) };
        f4 hv1 = { bf2f(hi[4]), bf2f(hi[5]), bf2f(hi[6]), bf2f(hi[7]) };
        f4 l0 = fa - hv0, l1 = fb - hv1;
        u16x8 lo = { f2bf(l0.x), f2bf(l0.y), f2bf(l0.z), f2bf(l0.w),
                     f2bf(l1.x), f2bf(l1.y), f2bf(l1.z), f2bf(l1.w) };
        *(u16x8*)&featsB[e]  = hi;
        *(u16x8*)&featsLo[e] = lo;
    }
}

// ---------------------------------------------------------------------------
// K1b: k_sim — sim = feats(hi/lo) @ M(hi/lo)^T (3-pass MFMA, lo*lo dropped);
//      softmax -> wBg. 64 rows/block, 4 waves, wave-exclusive rows ->
//      barrier-free. A-panels (KP=64) staged via gload_lds from LLC-warm
//      featsB/featsLo, double-buffered, swizzled source + swizzled ds_read
//      (<=2-way banks). B-frags streamed from L2 (256 KB resident).
// ---------------------------------------------------------------------------
__global__ __launch_bounds__(256) void k_sim(
    const u16* __restrict__ featsB, const u16* __restrict__ featsLo,
    const u16* __restrict__ memHi, const u16* __restrict__ memLo,
    u16* __restrict__ wBg)
{
    __shared__ u16 S[2][4][2][1024];  // [buf][wave][hi/lo][16 rows x 64 cols]

    const int tid  = threadIdx.x;
    const int lane = tid & 63, w = tid >> 6;
    const int fr   = lane & 15, sg = lane >> 4;
    const int fk   = sg * 8, jr = sg * 4;
    const int r0   = blockIdx.x * 64;
    const int rowbase = r0 + 16 * w;          // this wave's 16 rows

    // staging lane geometry: per gload, 64 lanes = 8 rows x 8 slots of 16B
    const int lrow = lane >> 3;               // row within 8-row chunk
    const int lslot = lane & 7;               // LDS 16B slot
    const int srcsl = (lslot ^ lrow) * 8;     // pre-swizzled source col (u16)

    auto stage = [&](int b, int p) {
        #pragma unroll
        for (int g = 0; g < 2; ++g) {
            const int r = rowbase + g * 8 + lrow;
            GLOAD_LDS16(featsB  + (size_t)r * HD + p * 64 + srcsl,
                        &S[b][w][0][g * 512]);
            GLOAD_LDS16(featsLo + (size_t)r * HD + p * 64 + srcsl,
                        &S[b][w][1][g * 512]);
        }
    };

    f32x4 acc[4] = {};                        // sim[16 rows][m = n*16 + fr]

    stage(0, 0);
    for (int p = 0; p < 16; ++p) {
        const int b = p & 1;
        if (p < 15) { stage(b ^ 1, p + 1); WAITV4; }
        else        { WAITV0; }
        SCHB;

        #pragma unroll
        for (int ks = 0; ks < 2; ++ks) {
            const int sl = ((ks * 4 + sg) ^ (fr & 7)) * 8;
            s16x8 aH = *(const s16x8*)&S[b][w][0][fr * 64 + sl];
            s16x8 aL = *(const s16x8*)&S[b][w][1][fr * 64 + sl];
            #pragma unroll
            for (int n = 0; n < 4; ++n) {
                const size_t mb = (size_t)(n * 16 + fr) * HD + p * 64 + ks * 32 + fk;
                s16x8 bH = *(const s16x8*)&memHi[mb];
                s16x8 bL = *(const s16x8*)&memLo[mb];
                acc[n] = __builtin_amdgcn_mfma_f32_16x16x32_bf16(aH, bH, acc[n], 0, 0, 0);
                acc[n] = __builtin_amdgcn_mfma_f32_16x16x32_bf16(aH, bL, acc[n], 0, 0, 0);
                acc[n] = __builtin_amdgcn_mfma_f32_16x16x32_bf16(aL, bH, acc[n], 0, 0, 0);
            }
        }
    }

    // softmax over m (50)
    #pragma unroll
    for (int j = 0; j < 4; ++j) {
        const int rg = r0 + 16 * w + jr + j;
        float v[4];
        float mx = -1e30f;
        #pragma unroll
        for (int n = 0; n < 4; ++n) {
            v[n] = acc[n][j];
            const int m = n * 16 + fr;
            if (m < MEMN) mx = fmaxf(mx, v[n]);
        }
        #pragma unroll
        for (int d = 1; d < 16; d <<= 1) mx = fmaxf(mx, __shfl_xor(mx, d));
        float e[4], s = 0.f;
        #pragma unroll
        for (int n = 0; n < 4; ++n) {
            const int m = n * 16 + fr;
            e[n] = (m < MEMN) ? __expf(v[n] - mx) : 0.f;
            s += e[n];
        }
        #pragma unroll
        for (int d = 1; d < 16; d <<= 1) s += __shfl_xor(s, d);
        const float inv = 1.f / s;
        #pragma unroll
        for (int n = 0; n < 4; ++n)
            wBg[(size_t)rg * 64 + n * 16 + fr] = f2bf(e[n] * inv); // 0 pad m>=50
    }
}

// ---------------------------------------------------------------------------
// K2: out = featsB + sigmoid([featsB|w]@[Wf;MWm] + b) * (w@M).
//     Round-10 exact: K=1088 (34 tiles). BM=256, BN=128, BK=32, 8 waves
//     (4Mx2N, 512 thr). 2 LDS buffers dist-1 (48 KB -> 3 blocks/CU),
//     vmcnt(3). accR = w@M per-(m,n) in epilogue.
// ---------------------------------------------------------------------------
__global__ __launch_bounds__(512) void k_gate_out(
    const u16* __restrict__ featsB, const u16* __restrict__ wBg,
    const u16* __restrict__ gwB, const u16* __restrict__ memT,
    const u16* __restrict__ MWmT, const float* __restrict__ gb,
    float* __restrict__ out)
{
    __shared__ u16 As[2][256 * 32];   // 2 x 16 KB
    __shared__ u16 Bs[2][128 * 32];   // 2 x 8 KB

    const int tid = threadIdx.x;
    int bid = blockIdx.x;
    bid = (bid & 7) * 200 + (bid >> 3);      // XCD swizzle (1600 % 8 == 0)
    const int mt = bid >> 3, nt = bid & 7;   // 200 x 8 tiles
    const int row0 = mt * 256, col0 = nt * 128;
    const int lane = tid & 63, wave = tid >> 6;
    const int wm = wave >> 1, wn = wave & 1; // 4M x 2N (64x64 each)
    const int fr = lane & 15, fk = (lane >> 4) * 8;

    f32x4 acc[4][4] = {};

    const int sr = tid >> 2;                 // staging row 0..127
    const int sc = (tid & 3) * 8;            // staging col (elements)

    auto stage = [&](int buf, int kt) {
        if (kt < 32) {
            const int k0 = kt * 32;
            GLOAD_LDS16(featsB + (size_t)(row0 + sr) * HD + k0 + sc,       &As[buf][tid * 8]);
            GLOAD_LDS16(featsB + (size_t)(row0 + 128 + sr) * HD + k0 + sc, &As[buf][4096 + tid * 8]);
            GLOAD_LDS16(gwB + (size_t)(col0 + sr) * 2048 + k0 + sc,        &Bs[buf][tid * 8]);
        } else {
            const int k0 = (kt - 32) * 32;
            GLOAD_LDS16(wBg + (size_t)(row0 + sr) * 64 + k0 + sc,          &As[buf][tid * 8]);
            GLOAD_LDS16(wBg + (size_t)(row0 + 128 + sr) * 64 + k0 + sc,    &As[buf][4096 + tid * 8]);
            GLOAD_LDS16(MWmT + (size_t)(col0 + sr) * 64 + k0 + sc,         &Bs[buf][tid * 8]);
        }
    };

    stage(0, 0);
    int cur = 0;

    for (int kt = 0; kt < 34; ++kt) {
        if (kt < 33) {
            stage(cur ^ 1, kt + 1);
            WAITV3;                          // cur's 3 loads done
        } else {
            WAITV0;
        }
        __builtin_amdgcn_s_barrier();
        SCHB;

        s16x8 aF[4], bF[4];
        #pragma unroll
        for (int m = 0; m < 4; ++m)
            aF[m] = *(const s16x8*)&As[cur][(wm * 64 + m * 16 + fr) * 32 + fk];
        #pragma unroll
        for (int n = 0; n < 4; ++n)
            bF[n] = *(const s16x8*)&Bs[cur][(wn * 64 + n * 16 + fr) * 32 + fk];
        #pragma unroll
        for (int m = 0; m < 4; ++m)
            #pragma unroll
            for (int n = 0; n < 4; ++n)
                acc[m][n] = __builtin_amdgcn_mfma_f32_16x16x32_bf16(
                    aF[m], bF[n], acc[m][n], 0, 0, 0);

        SCHB;
        __builtin_amdgcn_s_barrier();
        cur ^= 1;
    }

    // epilogue: accR = w@M per (m,n); out = feats + sigmoid(acc+b)*accR
    #pragma unroll
    for (int m = 0; m < 4; ++m) {
        const size_t ab = (size_t)(row0 + wm * 64 + m * 16 + fr) * 64 + fk;
        s16x8 a2_0 = *(const s16x8*)&wBg[ab];
        s16x8 a2_1 = *(const s16x8*)&wBg[ab + 32];
        #pragma unroll
        for (int n = 0; n < 4; ++n) {
            const size_t cb = (size_t)(col0 + wn * 64 + n * 16 + fr) * 64 + fk;
            s16x8 bT0 = *(const s16x8*)&memT[cb];
            s16x8 bT1 = *(const s16x8*)&memT[cb + 32];
            f32x4 accR = {};
            accR = __builtin_amdgcn_mfma_f32_16x16x32_bf16(a2_0, bT0, accR, 0, 0, 0);
            accR = __builtin_amdgcn_mfma_f32_16x16x32_bf16(a2_1, bT1, accR, 0, 0, 0);

            const int crow = row0 + wm * 64 + m * 16 + (lane >> 4) * 4;
            const int ccol = col0 + wn * 64 + n * 16 + fr;
            const float bias = gb[ccol];
            #pragma unroll
            for (int j = 0; j < 4; ++j) {
                const size_t idx = (size_t)(crow + j) * HD + ccol;
                const float fe = bf2f(featsB[idx]);
                const float pre = acc[m][n][j] + bias;
                const float g = 1.0f / (1.0f + __expf(-pre));
                out[idx] = fe + g * accR[j];
            }
        }
    }
}

// ---------------------------------------------------------------------------
extern "C" void kernel_launch(void* const* d_in, const int* in_sizes, int n_in,
                              void* d_out, int out_size, void* d_ws, size_t ws_size,
                              hipStream_t stream)
{
    const float* x   = (const float*)d_in[0];
    const float* sm  = (const float*)d_in[1];
    const float* pos = (const float*)d_in[2];
    const float* gw  = (const float*)d_in[3];
    const float* gb  = (const float*)d_in[4];
    float* out = (float*)d_out;

    u16* featsB = (u16*)d_ws;                          // 51200*1024 (100 MB)
    u16* gwB    = featsB + (size_t)RTOT * HD;          // 1024*2048
    u16* wBg    = gwB + (size_t)HD * 2048;             // 51200*64
    u16* memHi  = wBg + (size_t)RTOT * 64;             // 64*1024
    u16* memLo  = memHi + 64 * HD;                     // 64*1024
    u16* memT   = memLo + 64 * HD;                     // 1024*64
    u16* MWmT   = memT + (size_t)HD * 64;              // 1024*64

    // featsLo aliases d_out: consumed by k_sim, then k_gate_out overwrites
    // all of d_out with final results (sequential kernels on one stream).
    u16* featsLo = (u16*)d_out;                        // 51200*1024 bf16

    k_cvt_w<<<dim3(1024), dim3(256), 0, stream>>>(gw, gwB);
    k_prep_mem<<<dim3(64), dim3(256), 0, stream>>>(sm, memHi, memLo, memT);
    k_mwm<<<dim3(16), dim3(256), 0, stream>>>(memHi, gwB, MWmT);
    k_feats<<<dim3(1600), dim3(256), 0, stream>>>(x, pos, featsB, featsLo);
    k_sim<<<dim3(RTOT / 64), dim3(256), 0, stream>>>(featsB, featsLo,
                                                     memHi, memLo, wBg);
    k_gate_out<<<dim3(1600), dim3(512), 0, stream>>>(featsB, wBg, gwB, memT,
                                                     MWmT, gb, out);
}

// Round 13
// 371.132 us; speedup vs baseline: 1.2705x; 1.2705x over previous
//
#include <hip/hip_runtime.h>
#include <cstdint>
#include <cstddef>

#define HD   1024
#define SEQL 200
#define MEMN 50
#define RTOT 51200   // 256 * 200
#define PK   72      // fHi/fLo row stride (64 + 8 pad -> 2-way banks, free)

typedef float  f4    __attribute__((ext_vector_type(4)));
typedef float  f32x4 __attribute__((ext_vector_type(4)));
typedef short  s16x8 __attribute__((ext_vector_type(8)));
typedef unsigned short u16;
typedef unsigned short u16x4 __attribute__((ext_vector_type(4)));
typedef unsigned short u16x8 __attribute__((ext_vector_type(8)));

__device__ __forceinline__ u16 f2bf(float f) {
    unsigned u = __builtin_bit_cast(unsigned, f);
    u += 0x7FFFu + ((u >> 16) & 1u);          // RNE
    return (u16)(u >> 16);
}
__device__ __forceinline__ float bf2f(u16 h) {
    unsigned u = ((unsigned)h) << 16;
    return __builtin_bit_cast(float, u);
}

#define GLOAD_LDS16(g, l) __builtin_amdgcn_global_load_lds( \
    (const __attribute__((address_space(1))) unsigned int*)(g), \
    (__attribute__((address_space(3))) unsigned int*)(l), 16, 0, 0)

#define WAITV3 asm volatile("s_waitcnt vmcnt(3)" ::: "memory")
#define WAITV0 asm volatile("s_waitcnt vmcnt(0)" ::: "memory")
#define LGKMFENCE asm volatile("s_waitcnt lgkmcnt(0)" ::: "memory")
#define SCHB   __builtin_amdgcn_sched_barrier(0)

// ---------------------------------------------------------------------------
// K0a: gate_w f32 -> bf16, layout [o][2048] k-contig. Wf = cols 0..1023,
//      Wm = cols 1024..2047.
// ---------------------------------------------------------------------------
__global__ __launch_bounds__(256) void k_cvt_w(const float* __restrict__ gw,
                                               u16* __restrict__ gwB)
{
    const size_t i = ((size_t)blockIdx.x * 256 + threadIdx.x) * 8;
    f4 v0 = *(const f4*)&gw[i];
    f4 v1 = *(const f4*)&gw[i + 4];
    u16x4 b0 = { f2bf(v0.x), f2bf(v0.y), f2bf(v0.z), f2bf(v0.w) };
    u16x4 b1 = { f2bf(v1.x), f2bf(v1.y), f2bf(v1.z), f2bf(v1.w) };
    *(u16x4*)&gwB[i]     = b0;
    *(u16x4*)&gwB[i + 4] = b1;
}

// ---------------------------------------------------------------------------
// K0b: spatial memory prep.
//   memHi  [64][1024] bf16 linear (rows 50..63 zero)  — for k_mwm
//   memT   [1024][64] bf16 transposed                  — for k_gate epilogue
//   memSH/memSL [16][64][8slots][8] bf16, slot pre-swizzled s^(m&7)
//                                                      — for k_pre LDS staging
// ---------------------------------------------------------------------------
__global__ __launch_bounds__(256) void k_prep_mem(const float* __restrict__ sm,
                                                  u16* __restrict__ memHi,
                                                  u16* __restrict__ memT,
                                                  u16* __restrict__ memSH,
                                                  u16* __restrict__ memSL)
{
    const int idx = blockIdx.x * 256 + threadIdx.x;   // 16384 total
    const int m  = idx >> 8;
    const int h0 = (idx & 255) * 4;
    f4 v = {0.f, 0.f, 0.f, 0.f};
    if (m < MEMN) v = *(const f4*)&sm[(size_t)m * HD + h0];
    u16x4 hi = { f2bf(v.x), f2bf(v.y), f2bf(v.z), f2bf(v.w) };
    f4 hv = { bf2f(hi.x), bf2f(hi.y), bf2f(hi.z), bf2f(hi.w) };
    f4 lv = v - hv;
    u16x4 lo = { f2bf(lv.x), f2bf(lv.y), f2bf(lv.z), f2bf(lv.w) };
    *(u16x4*)&memHi[(size_t)m * HD + h0] = hi;
    memT[(size_t)(h0 + 0) * 64 + m] = hi.x;
    memT[(size_t)(h0 + 1) * 64 + m] = hi.y;
    memT[(size_t)(h0 + 2) * 64 + m] = hi.z;
    memT[(size_t)(h0 + 3) * 64 + m] = hi.w;
    // swizzled copies: panel p = h0>>6, slot s = (h0>>3)&7, elem e = h0&7
    const int p = h0 >> 6, s = (h0 >> 3) & 7, e = h0 & 7;
    const size_t sw = (size_t)p * 4096 + m * 64 + ((s ^ (m & 7)) << 3) + e;
    *(u16x4*)&memSH[sw] = hi;
    *(u16x4*)&memSL[sw] = lo;
}

// ---------------------------------------------------------------------------
// K0d: MWmT[o][m] = (M @ Wm)(m,o) as bf16, [1024][64].  MFMA, 16 blocks.
// ---------------------------------------------------------------------------
__global__ __launch_bounds__(256) void k_mwm(const u16* __restrict__ memHi,
                                             const u16* __restrict__ gwB,
                                             u16* __restrict__ MWmT)
{
    const int tid = threadIdx.x, lane = tid & 63, w = tid >> 6;
    const int fr = lane & 15, fk = (lane >> 4) * 8, jr = (lane >> 4) * 4;
    const int ob = blockIdx.x * 64 + w * 16;       // o-base of this wave
    f32x4 acc[4] = {};
    for (int ks = 0; ks < 32; ++ks) {
        s16x8 b = *(const s16x8*)&gwB[(size_t)(ob + fr) * 2048 + 1024 + ks * 32 + fk];
        #pragma unroll
        for (int mt = 0; mt < 4; ++mt) {
            s16x8 a = *(const s16x8*)&memHi[(size_t)(mt * 16 + fr) * HD + ks * 32 + fk];
            acc[mt] = __builtin_amdgcn_mfma_f32_16x16x32_bf16(a, b, acc[mt], 0, 0, 0);
        }
    }
    #pragma unroll
    for (int mt = 0; mt < 4; ++mt)
        #pragma unroll
        for (int j = 0; j < 4; ++j)
            MWmT[(size_t)(ob + fr) * 64 + mt * 16 + jr + j] = f2bf(acc[mt][j]);
}

// ---------------------------------------------------------------------------
// K1: fused feats+sim+softmax, vmem-free MFMA section.
//   feats = x + pos (f32); featsB = bf16(feats); lo = bf16(feats - hi);
//   sim = feats(hi/lo) @ M(hi/lo)^T (3-pass, lo*lo dropped); softmax -> wBg.
//   64 rows/block, 4 waves, KP=64 (16 panels). Mem panel (hi+lo, 16 KB)
//   double-buffered in LDS via gload_lds from pre-swizzled memSH/memSL.
//   Per panel: WAITV0 -> convert -> lgkm0 -> s_barrier (publish mem(p);
//   all waves done reading other buf) -> issue mem(p+1)+x(p+1) -> MFMA(DS).
// ---------------------------------------------------------------------------
__global__ __launch_bounds__(256) void k_pre(
    const float* __restrict__ x, const float* __restrict__ pos,
    const u16* __restrict__ memSH, const u16* __restrict__ memSL,
    u16* __restrict__ featsB, u16* __restrict__ wBg)
{
    __shared__ u16 fHi[64 * PK];        // 9.2 KB
    __shared__ u16 fLo[64 * PK];        // 9.2 KB
    __shared__ u16 memH[2][64 * 64];    // 16 KB
    __shared__ u16 memL[2][64 * 64];    // 16 KB   (total 50.4 KB -> 3 blk/CU)

    const int tid  = threadIdx.x;
    const int r0   = blockIdx.x * 64;
    const int lane = tid & 63, w = tid >> 6;
    const int fr   = lane & 15, sg = lane >> 4;
    const int fk   = sg * 8, jr = sg * 4;

    const int srow = tid >> 2;          // wave-exclusive rows 16w..16w+15
    const int scol = (tid & 3) * 16;    // 16 contiguous cols per thread
    const int prow = (r0 + srow) % SEQL;
    const float* xrow = &x[(size_t)(r0 + srow) * HD];
    const float* prp  = &pos[(size_t)prow * HD];

    f4 xa[4], pa[4];
    #pragma unroll
    for (int i = 0; i < 4; ++i) {
        xa[i] = *(const f4*)&xrow[scol + i * 4];
        pa[i] = *(const f4*)&prp[scol + i * 4];
    }
    // prologue: mem panel 0 -> buf 0 (cooperative, linear dest)
    GLOAD_LDS16(memSH + tid * 8,        &memH[0][tid * 8]);
    GLOAD_LDS16(memSH + 2048 + tid * 8, &memH[0][2048 + tid * 8]);
    GLOAD_LDS16(memSL + tid * 8,        &memL[0][tid * 8]);
    GLOAD_LDS16(memSL + 2048 + tid * 8, &memL[0][2048 + tid * 8]);

    f32x4 acc[4] = {};                  // sim[16 rows][m = n*16 + fr]

    for (int p = 0; p < 16; ++p) {
        const int b = p & 1;
        WAITV0;                         // x(p) + my mem(p) portions retired

        // ---- convert panel p: regs -> fHi/fLo LDS + featsB store ----
        {
            f4 f0 = xa[0] + pa[0], f1 = xa[1] + pa[1];
            f4 f2 = xa[2] + pa[2], f3 = xa[3] + pa[3];
            u16x8 h0 = { f2bf(f0.x), f2bf(f0.y), f2bf(f0.z), f2bf(f0.w),
                         f2bf(f1.x), f2bf(f1.y), f2bf(f1.z), f2bf(f1.w) };
            u16x8 h1 = { f2bf(f2.x), f2bf(f2.y), f2bf(f2.z), f2bf(f2.w),
                         f2bf(f3.x), f2bf(f3.y), f2bf(f3.z), f2bf(f3.w) };
            *(u16x8*)&featsB[(size_t)(r0 + srow) * HD + p * 64 + scol]     = h0;
            *(u16x8*)&featsB[(size_t)(r0 + srow) * HD + p * 64 + scol + 8] = h1;
            f4 hv0 = { bf2f(h0[0]), bf2f(h0[1]), bf2f(h0[2]), bf2f(h0[3]) };
            f4 hv1 = { bf2f(h0[4]), bf2f(h0[5]), bf2f(h0[6]), bf2f(h0[7]) };
            f4 hv2 = { bf2f(h1[0]), bf2f(h1[1]), bf2f(h1[2]), bf2f(h1[3]) };
            f4 hv3 = { bf2f(h1[4]), bf2f(h1[5]), bf2f(h1[6]), bf2f(h1[7]) };
            f4 l0 = f0 - hv0, l1 = f1 - hv1, l2 = f2 - hv2, l3 = f3 - hv3;
            u16x8 lo0 = { f2bf(l0.x), f2bf(l0.y), f2bf(l0.z), f2bf(l0.w),
                          f2bf(l1.x), f2bf(l1.y), f2bf(l1.z), f2bf(l1.w) };
            u16x8 lo1 = { f2bf(l2.x), f2bf(l2.y), f2bf(l2.z), f2bf(l2.w),
                          f2bf(l3.x), f2bf(l3.y), f2bf(l3.z), f2bf(l3.w) };
            *(u16x8*)&fHi[srow * PK + scol]     = h0;
            *(u16x8*)&fHi[srow * PK + scol + 8] = h1;
            *(u16x8*)&fLo[srow * PK + scol]     = lo0;
            *(u16x8*)&fLo[srow * PK + scol + 8] = lo1;
        }
        LGKMFENCE;                      // wave-lockstep: whole wave's ds_writes done
        __builtin_amdgcn_s_barrier();   // publish mem(p); all done reading buf b^1

        // ---- issue next panel's mem staging + x/pos prefetch ----
        if (p < 15) {
            const size_t mo = (size_t)(p + 1) * 4096;
            GLOAD_LDS16(memSH + mo + tid * 8,        &memH[b ^ 1][tid * 8]);
            GLOAD_LDS16(memSH + mo + 2048 + tid * 8, &memH[b ^ 1][2048 + tid * 8]);
            GLOAD_LDS16(memSL + mo + tid * 8,        &memL[b ^ 1][tid * 8]);
            GLOAD_LDS16(memSL + mo + 2048 + tid * 8, &memL[b ^ 1][2048 + tid * 8]);
            const int c = (p + 1) * 64 + scol;
            #pragma unroll
            for (int i = 0; i < 4; ++i) {
                xa[i] = *(const f4*)&xrow[c + i * 4];
                pa[i] = *(const f4*)&prp[c + i * 4];
            }
        }

        // ---- sim MFMA: pure DS (fHi/fLo + swizzled mem panel) ----
        #pragma unroll
        for (int ks = 0; ks < 2; ++ks) {
            s16x8 aH = *(const s16x8*)&fHi[(16 * w + fr) * PK + ks * 32 + fk];
            s16x8 aL = *(const s16x8*)&fLo[(16 * w + fr) * PK + ks * 32 + fk];
            #pragma unroll
            for (int n = 0; n < 4; ++n) {
                const int m = n * 16 + fr;
                const int slot = ((ks * 4 + sg) ^ (m & 7)) * 8;
                s16x8 bH = *(const s16x8*)&memH[b][m * 64 + slot];
                s16x8 bL = *(const s16x8*)&memL[b][m * 64 + slot];
                acc[n] = __builtin_amdgcn_mfma_f32_16x16x32_bf16(aH, bH, acc[n], 0, 0, 0);
                acc[n] = __builtin_amdgcn_mfma_f32_16x16x32_bf16(aH, bL, acc[n], 0, 0, 0);
                acc[n] = __builtin_amdgcn_mfma_f32_16x16x32_bf16(aL, bH, acc[n], 0, 0, 0);
            }
        }
    }

    // softmax over m (50)
    #pragma unroll
    for (int j = 0; j < 4; ++j) {
        const int rg = r0 + 16 * w + jr + j;
        float v[4];
        float mx = -1e30f;
        #pragma unroll
        for (int n = 0; n < 4; ++n) {
            v[n] = acc[n][j];
            const int m = n * 16 + fr;
            if (m < MEMN) mx = fmaxf(mx, v[n]);
        }
        #pragma unroll
        for (int d = 1; d < 16; d <<= 1) mx = fmaxf(mx, __shfl_xor(mx, d));
        float e[4], s = 0.f;
        #pragma unroll
        for (int n = 0; n < 4; ++n) {
            const int m = n * 16 + fr;
            e[n] = (m < MEMN) ? __expf(v[n] - mx) : 0.f;
            s += e[n];
        }
        #pragma unroll
        for (int d = 1; d < 16; d <<= 1) s += __shfl_xor(s, d);
        const float inv = 1.f / s;
        #pragma unroll
        for (int n = 0; n < 4; ++n)
            wBg[(size_t)rg * 64 + n * 16 + fr] = f2bf(e[n] * inv); // 0 pad m>=50
    }
}

// ---------------------------------------------------------------------------
// K2: out = featsB + sigmoid([featsB|w]@[Wf;MWm] + b) * (w@M).
//     Round-12 exact: K=1088 (34 tiles). BM=256, BN=128, BK=32, 8 waves
//     (4Mx2N, 512 thr). 2 LDS buffers dist-1 (48 KB -> 3 blocks/CU),
//     vmcnt(3). accR = w@M per-(m,n) in epilogue.
// ---------------------------------------------------------------------------
__global__ __launch_bounds__(512) void k_gate_out(
    const u16* __restrict__ featsB, const u16* __restrict__ wBg,
    const u16* __restrict__ gwB, const u16* __restrict__ memT,
    const u16* __restrict__ MWmT, const float* __restrict__ gb,
    float* __restrict__ out)
{
    __shared__ u16 As[2][256 * 32];   // 2 x 16 KB
    __shared__ u16 Bs[2][128 * 32];   // 2 x 8 KB

    const int tid = threadIdx.x;
    int bid = blockIdx.x;
    bid = (bid & 7) * 200 + (bid >> 3);      // XCD swizzle (1600 % 8 == 0)
    const int mt = bid >> 3, nt = bid & 7;   // 200 x 8 tiles
    const int row0 = mt * 256, col0 = nt * 128;
    const int lane = tid & 63, wave = tid >> 6;
    const int wm = wave >> 1, wn = wave & 1; // 4M x 2N (64x64 each)
    const int fr = lane & 15, fk = (lane >> 4) * 8;

    f32x4 acc[4][4] = {};

    const int sr = tid >> 2;                 // staging row 0..127
    const int sc = (tid & 3) * 8;            // staging col (elements)

    auto stage = [&](int buf, int kt) {
        if (kt < 32) {
            const int k0 = kt * 32;
            GLOAD_LDS16(featsB + (size_t)(row0 + sr) * HD + k0 + sc,       &As[buf][tid * 8]);
            GLOAD_LDS16(featsB + (size_t)(row0 + 128 + sr) * HD + k0 + sc, &As[buf][4096 + tid * 8]);
            GLOAD_LDS16(gwB + (size_t)(col0 + sr) * 2048 + k0 + sc,        &Bs[buf][tid * 8]);
        } else {
            const int k0 = (kt - 32) * 32;
            GLOAD_LDS16(wBg + (size_t)(row0 + sr) * 64 + k0 + sc,          &As[buf][tid * 8]);
            GLOAD_LDS16(wBg + (size_t)(row0 + 128 + sr) * 64 + k0 + sc,    &As[buf][4096 + tid * 8]);
            GLOAD_LDS16(MWmT + (size_t)(col0 + sr) * 64 + k0 + sc,         &Bs[buf][tid * 8]);
        }
    };

    stage(0, 0);
    int cur = 0;

    for (int kt = 0; kt < 34; ++kt) {
        if (kt < 33) {
            stage(cur ^ 1, kt + 1);
            WAITV3;                          // cur's 3 loads done
        } else {
            WAITV0;
        }
        __builtin_amdgcn_s_barrier();
        SCHB;

        s16x8 aF[4], bF[4];
        #pragma unroll
        for (int m = 0; m < 4; ++m)
            aF[m] = *(const s16x8*)&As[cur][(wm * 64 + m * 16 + fr) * 32 + fk];
        #pragma unroll
        for (int n = 0; n < 4; ++n)
            bF[n] = *(const s16x8*)&Bs[cur][(wn * 64 + n * 16 + fr) * 32 + fk];
        #pragma unroll
        for (int m = 0; m < 4; ++m)
            #pragma unroll
            for (int n = 0; n < 4; ++n)
                acc[m][n] = __builtin_amdgcn_mfma_f32_16x16x32_bf16(
                    aF[m], bF[n], acc[m][n], 0, 0, 0);

        SCHB;
        __builtin_amdgcn_s_barrier();
        cur ^= 1;
    }

    // epilogue: accR = w@M per (m,n); out = feats + sigmoid(acc+b)*accR
    #pragma unroll
    for (int m = 0; m < 4; ++m) {
        const size_t ab = (size_t)(row0 + wm * 64 + m * 16 + fr) * 64 + fk;
        s16x8 a2_0 = *(const s16x8*)&wBg[ab];
        s16x8 a2_1 = *(const s16x8*)&wBg[ab + 32];
        #pragma unroll
        for (int n = 0; n < 4; ++n) {
            const size_t cb = (size_t)(col0 + wn * 64 + n * 16 + fr) * 64 + fk;
            s16x8 bT0 = *(const s16x8*)&memT[cb];
            s16x8 bT1 = *(const s16x8*)&memT[cb + 32];
            f32x4 accR = {};
            accR = __builtin_amdgcn_mfma_f32_16x16x32_bf16(a2_0, bT0, accR, 0, 0, 0);
            accR = __builtin_amdgcn_mfma_f32_16x16x32_bf16(a2_1, bT1, accR, 0, 0, 0);

            const int crow = row0 + wm * 64 + m * 16 + (lane >> 4) * 4;
            const int ccol = col0 + wn * 64 + n * 16 + fr;
            const float bias = gb[ccol];
            #pragma unroll
            for (int j = 0; j < 4; ++j) {
                const size_t idx = (size_t)(crow + j) * HD + ccol;
                const float fe = bf2f(featsB[idx]);
                const float pre = acc[m][n][j] + bias;
                const float g = 1.0f / (1.0f + __expf(-pre));
                out[idx] = fe + g * accR[j];
            }
        }
    }
}

// ---------------------------------------------------------------------------
extern "C" void kernel_launch(void* const* d_in, const int* in_sizes, int n_in,
                              void* d_out, int out_size, void* d_ws, size_t ws_size,
                              hipStream_t stream)
{
    const float* x   = (const float*)d_in[0];
    const float* sm  = (const float*)d_in[1];
    const float* pos = (const float*)d_in[2];
    const float* gw  = (const float*)d_in[3];
    const float* gb  = (const float*)d_in[4];
    float* out = (float*)d_out;

    u16* featsB = (u16*)d_ws;                          // 51200*1024 (100 MB)
    u16* gwB    = featsB + (size_t)RTOT * HD;          // 1024*2048
    u16* wBg    = gwB + (size_t)HD * 2048;             // 51200*64
    u16* memHi  = wBg + (size_t)RTOT * 64;             // 64*1024
    u16* memT   = memHi + 64 * HD;                     // 1024*64
    u16* MWmT   = memT + (size_t)HD * 64;              // 1024*64
    u16* memSH  = MWmT + (size_t)HD * 64;              // 16*64*64 swizzled
    u16* memSL  = memSH + (size_t)64 * HD;             // 16*64*64 swizzled

    k_cvt_w<<<dim3(1024), dim3(256), 0, stream>>>(gw, gwB);
    k_prep_mem<<<dim3(64), dim3(256), 0, stream>>>(sm, memHi, memT, memSH, memSL);
    k_mwm<<<dim3(16), dim3(256), 0, stream>>>(memHi, gwB, MWmT);
    k_pre<<<dim3(RTOT / 64), dim3(256), 0, stream>>>(x, pos, memSH, memSL,
                                                     featsB, wBg);
    k_gate_out<<<dim3(1600), dim3(512), 0, stream>>>(featsB, wBg, gwB, memT,
                                                     MWmT, gb, out);
}